// Round 7
// baseline (1737.749 us; speedup 1.0000x reference)
//
#include <hip/hip_runtime.h>
#include <hip/hip_bf16.h>
#include <math.h>

#define EPS 1e-5f
#define MAXN (1.0f - EPS)
#define MINN 1e-10f

constexpr int D = 2048;      // Dh == Din == 2048 for this problem

typedef unsigned short u16;
typedef __bf16 bf16x8 __attribute__((ext_vector_type(8)));
typedef float floatx4 __attribute__((ext_vector_type(4)));

// ---------- small helpers ----------

__device__ __forceinline__ u16 f2bf(float f) {
    union { float f; unsigned u; } v; v.f = f;
    unsigned r = v.u + 0x7FFFu + ((v.u >> 16) & 1u);   // RNE
    return (u16)(r >> 16);
}

__device__ __forceinline__ float bf2f(u16 b) {
    union { unsigned u; float f; } v; v.u = ((unsigned)b) << 16; return v.f;
}

__device__ __forceinline__ void load_bf8(const u16* p, float* d) {
    uint4 r = *(const uint4*)p;
    unsigned w[4] = {r.x, r.y, r.z, r.w};
    #pragma unroll
    for (int i = 0; i < 4; ++i) {
        d[2 * i]     = bf2f((u16)(w[i] & 0xFFFFu));
        d[2 * i + 1] = bf2f((u16)(w[i] >> 16));
    }
}

__device__ __forceinline__ void store_bf8(u16* p, const float* s) {
    u16 pk[8];
    #pragma unroll
    for (int i = 0; i < 8; ++i) pk[i] = f2bf(s[i]);
    *(uint4*)p = *(const uint4*)pk;
}

__device__ __forceinline__ void load_f8(const float* p, float* d) {
    *(float4*)(d)     = *(const float4*)(p);
    *(float4*)(d + 4) = *(const float4*)(p + 4);
}

__device__ __forceinline__ void store_f8(float* p, const float* s) {
    *(float4*)(p)     = *(const float4*)(s);
    *(float4*)(p + 4) = *(const float4*)(s + 4);
}

__device__ __forceinline__ float artanh_(float x) {
    x = fminf(fmaxf(x, -1.0f + EPS), 1.0f - EPS);
    return 0.5f * logf((1.0f + x) / (1.0f - x));
}

__device__ __forceinline__ float sigmoid_(float x) {
    return 1.0f / (1.0f + expf(-x));
}

__device__ __forceinline__ void gl_lds16(const u16* g, u16* l) {
    __builtin_amdgcn_global_load_lds(
        (const __attribute__((address_space(1))) unsigned int*)g,
        (__attribute__((address_space(3))) unsigned int*)l, 16, 0, 0);
}

// N simultaneous block-wide sums, ONE barrier pair. 256 threads / 4 waves.
template<int N>
__device__ __forceinline__ void block_sums(float* v, float* sbuf) {
    #pragma unroll
    for (int n = 0; n < N; ++n)
        #pragma unroll
        for (int off = 32; off >= 1; off >>= 1) v[n] += __shfl_xor(v[n], off, 64);
    int w = threadIdx.x >> 6;
    __syncthreads();                       // protect sbuf from previous call
    if ((threadIdx.x & 63) == 0) {
        #pragma unroll
        for (int n = 0; n < N; ++n) sbuf[w * N + n] = v[n];
    }
    __syncthreads();
    #pragma unroll
    for (int n = 0; n < N; ++n)
        v[n] = sbuf[n] + sbuf[N + n] + sbuf[2 * N + n] + sbuf[3 * N + n];
}

__device__ __forceinline__ void mmm_finish(float sum2, float g, float* coef, float* onorm) {
    float mxn = sqrtf(fmaxf(sum2, MINN));
    float tt  = tanhf(mxn * g);
    float on  = fminf(tt, MAXN);
    *coef = on / mxn;
    *onorm = on;
}

// mob_add with analytic |num|^2 (single reduction). u <- proj(mob_add(u,v)).
__device__ __forceinline__ float mob_apply(float* u, const float* v,
                                           float u2, float v2, float duv) {
    float cu  = 1.f + 2.f * duv + v2;
    float cv  = 1.f - u2;
    float den = fmaxf(1.f + 2.f * duv + u2 * v2, MINN);
    float s2  = cu * cu * u2 + 2.f * cu * cv * duv + cv * cv * v2;
    float n   = sqrtf(fmaxf(s2 / (den * den), MINN));
    float sc  = ((n > MAXN) ? MAXN / n : 1.f) / den;
    #pragma unroll
    for (int i = 0; i < 8; ++i) u[i] = sc * (cu * u[i] + cv * v[i]);
    return fminf(n, MAXN);
}

// ---------- device-scope flag helpers (padded counters, bounded spin) ----------

struct Flag { unsigned v; unsigned pad[15]; };          // one cacheline each
struct FlagBlk { Flag pcnt; Flag wcnt[5]; Flag gcnt[16]; };

__device__ __forceinline__ void signal_cnt(unsigned* p) {
    __syncthreads();                 // all block writes done
    __threadfence();                 // device-scope release
    if (threadIdx.x == 0) atomicAdd(p, 1u);
}

__device__ __forceinline__ void wait_cnt(unsigned* p, unsigned tgt) {
    if (threadIdx.x == 0) {
        unsigned n = 0;
        while (__hip_atomic_load(p, __ATOMIC_RELAXED, __HIP_MEMORY_SCOPE_AGENT) < tgt
               && n < (1u << 22)) {   // bounded: cannot hang
            __builtin_amdgcn_s_sleep(8);
            ++n;
        }
    }
    __syncthreads();
    __threadfence();                 // device-scope acquire
}

// ---------- transpose helper: one 64x64 f32 -> bf16^T tile through LDS ----------

__device__ __forceinline__ void trans_tile(const float* W, u16* Wt,
                                           int n0, int k0, float* tile) {
    int t = threadIdx.x;
    int lr = t >> 4, lc = (t & 15) * 4;
    #pragma unroll
    for (int p = 0; p < 4; ++p) {
        int r = lr + p * 16;
        float4 v = *(const float4*)(W + (size_t)(k0 + r) * D + n0 + lc);
        tile[r * 65 + lc + 0] = v.x;
        tile[r * 65 + lc + 1] = v.y;
        tile[r * 65 + lc + 2] = v.z;
        tile[r * 65 + lc + 3] = v.w;
    }
    __syncthreads();
    int wn = t >> 3, ws = (t & 7) * 8;
    #pragma unroll
    for (int p = 0; p < 2; ++p) {
        int n = wn + p * 32;
        u16 pk[8];
        #pragma unroll
        for (int j = 0; j < 8; ++j) pk[j] = f2bf(tile[(ws + j) * 65 + n]);
        *(uint4*)(Wt + (size_t)(n0 + n) * D + k0 + ws) = *(uint4*)pk;
    }
}

// ---------- GEMM core (m97-style, BK=64, swizzled global_load_lds) ----------

template<int KLEN, typename CT>
__device__ __forceinline__ void gemm_body(const u16* __restrict__ A,
                                          const u16* __restrict__ W,
                                          CT* __restrict__ C, int koff,
                                          int bxi, int byi,
                                          u16* As, u16* Ws) {
    int t = threadIdx.x;
    int wave = t >> 6, lane = t & 63;
    int wr = wave >> 1, wc = wave & 1;       // 2x2 wave grid, each 64x64
    int quad = lane >> 4, l16 = lane & 15;
    int brow = byi * 128, bcol = bxi * 128;

    int srow = 32 * wave + (lane >> 3);
    int sseg = (lane & 7) ^ ((lane >> 3) & 7);
    const u16* pa = A + (size_t)(brow + srow) * D + koff + sseg * 8;
    const u16* pw = W + (size_t)(bcol + srow) * D + koff + sseg * 8;
    u16* lbA = &As[wave * 2048];             // wave-uniform LDS bases
    u16* lbW = &Ws[wave * 2048];

    floatx4 acc[4][4];
    #pragma unroll
    for (int i = 0; i < 4; ++i)
        #pragma unroll
        for (int j = 0; j < 4; ++j)
            #pragma unroll
            for (int e = 0; e < 4; ++e) acc[i][j][e] = 0.f;

    int xsw = l16 & 7;                       // fragment-read swizzle term

    for (int k0 = 0; k0 < KLEN; k0 += 64) {
        __syncthreads();
        #pragma unroll
        for (int i = 0; i < 4; ++i) {
            gl_lds16(pa + (size_t)(8 * i) * D + k0, lbA + i * 512);
            gl_lds16(pw + (size_t)(8 * i) * D + k0, lbW + i * 512);
        }
        __syncthreads();

        #pragma unroll
        for (int kk = 0; kk < 2; ++kk) {
            bf16x8 af[4], bfv[4];
            int ps = ((kk * 4 + quad) ^ xsw) * 8;
            #pragma unroll
            for (int i = 0; i < 4; ++i)
                af[i] = *(const bf16x8*)(&As[(wr * 64 + i * 16 + l16) * 64 + ps]);
            #pragma unroll
            for (int j = 0; j < 4; ++j)
                bfv[j] = *(const bf16x8*)(&Ws[(wc * 64 + j * 16 + l16) * 64 + ps]);
            #pragma unroll
            for (int i = 0; i < 4; ++i)
                #pragma unroll
                for (int j = 0; j < 4; ++j)
                    acc[i][j] = __builtin_amdgcn_mfma_f32_16x16x32_bf16(af[i], bfv[j], acc[i][j], 0, 0, 0);
        }
    }

    #pragma unroll
    for (int i = 0; i < 4; ++i) {
        #pragma unroll
        for (int j = 0; j < 4; ++j) {
            int row = brow + wr * 64 + i * 16 + quad * 4;
            int col = bcol + wc * 64 + j * 16 + l16;
            #pragma unroll
            for (int r = 0; r < 4; ++r) {
                float val = acc[i][j][r];
                if constexpr (sizeof(CT) == 2)
                    C[(size_t)(row + r) * D + col] = (CT)f2bf(val);
                else
                    C[(size_t)(row + r) * D + col] = (CT)val;
            }
        }
    }
}

// ---------- fused A: [transpose+proj producers | G1 GEMM consumers] ----------
// blocks 0..1023: 2 proj row-pairs + 5 weight tiles (order = G1 z order, w_h last)
// blocks 1024..2047: G1 GEMM, spins on its weight counter + proj counter.
// Capacity: 32KB LDS + launch_bounds(256,5) => 5 blocks/CU = 1280 resident
// >= 1024 spinners + 256 workers: deadlock-free regardless of dispatch order.

struct FABatch {
    const float* Wsrc[5]; u16* Wdst[5];       // write order: w_z,u_z,w_r,u_r,w_h
    const float* hx; const float* h;
    u16* hx_bf; u16* h_bf; float* g_x; float* g_h;
    const u16* A[4]; const u16* W[4]; u16* C[4];
    FlagBlk* fl;
};

__global__ __launch_bounds__(256, 5) void fused_a(FABatch fa) {
    __shared__ __align__(16) char smem[32768];
    int id = blockIdx.x;
    if (id < 1024) {
        float* tile = (float*)smem;
        // projection: rows 2*id, 2*id+1 (hx and h batched)
        #pragma unroll
        for (int rr = 0; rr < 2; ++rr) {
            int b = id * 2 + rr;
            size_t off = (size_t)b * D + threadIdx.x * 8;
            float xv[8], hv[8];
            load_f8(fa.hx + off, xv);
            load_f8(fa.h + off, hv);
            float s[2] = {0.f, 0.f};
            #pragma unroll
            for (int i = 0; i < 8; ++i) { s[0] += xv[i] * xv[i]; s[1] += hv[i] * hv[i]; }
            block_sums<2>(s, tile);
            float nx = sqrtf(fmaxf(s[0], MINN));
            float scx = (nx > MAXN) ? MAXN / nx : 1.0f;
            float nh = sqrtf(fmaxf(s[1], MINN));
            float sch = (nh > MAXN) ? MAXN / nh : 1.0f;
            #pragma unroll
            for (int i = 0; i < 8; ++i) { xv[i] *= scx; hv[i] *= sch; }
            store_bf8(fa.hx_bf + off, xv);
            store_bf8(fa.h_bf + off, hv);
            if (threadIdx.x == 0) {
                float xn = fminf(nx, MAXN), hn = fminf(nh, MAXN);
                fa.g_x[b] = artanh_(xn) / xn;
                fa.g_h[b] = artanh_(hn) / hn;
            }
        }
        signal_cnt(&fa.fl->pcnt.v);

        int n0 = (id & 31) * 64, k0 = (id >> 5) * 64;
        for (int s = 0; s < 5; ++s) {
            trans_tile(fa.Wsrc[s], fa.Wdst[s], n0, k0, tile);
            signal_cnt(&fa.fl->wcnt[s].v);   // syncthreads inside protects tile reuse
        }
    } else {
        int gid = id - 1024;
        int z = gid & 3, tt = gid >> 2;      // round-robin z for uniform start
        int bx = tt & 15, by = tt >> 4;
        wait_cnt(&fa.fl->wcnt[z].v, 1024);
        wait_cnt(&fa.fl->pcnt.v, 1024);
        gemm_body<2048, u16>(fa.A[z], fa.W[z], fa.C[z], 0, bx, by,
                             (u16*)smem, (u16*)(smem + 16384));
    }
}

// ---------- K4: fused middle (finish 4 matvecs, z, r, r_point_h) ----------

__global__ __launch_bounds__(256) void mid_kernel(
    const u16* __restrict__ c_wz, const u16* __restrict__ c_uz,
    const u16* __restrict__ c_wr, const u16* __restrict__ c_ur,
    const u16* __restrict__ h_bf,
    const float* __restrict__ g_x, const float* __restrict__ g_h,
    const float* __restrict__ b_z, const float* __restrict__ b_r,
    u16* __restrict__ z_out, u16* __restrict__ uxr_out,
    u16* __restrict__ rph_bf, float* __restrict__ g_rph) {
    __shared__ float sbuf[24];
    int b = blockIdx.x, t = threadIdx.x;
    size_t off = (size_t)b * D + t * 8;
    int cbase = t * 8;

    float wz[8], uz[8], wr2[8], ur2[8], hp[8], bz[8], br[8];
    load_bf8(c_wz + off, wz);
    load_bf8(c_uz + off, uz);
    load_bf8(c_wr + off, wr2);
    load_bf8(c_ur + off, ur2);
    load_bf8(h_bf + off, hp);
    load_f8(b_z + cbase, bz);
    load_f8(b_r + cbase, br);

    float s[6] = {0, 0, 0, 0, 0, 0};
    #pragma unroll
    for (int i = 0; i < 8; ++i) {
        s[0] += wz[i] * wz[i];  s[1] += uz[i] * uz[i];
        s[2] += wr2[i] * wr2[i]; s[3] += ur2[i] * ur2[i];
        s[4] += bz[i] * bz[i];  s[5] += br[i] * br[i];
    }
    block_sums<6>(s, sbuf);
    float gh = g_h[b], gx = g_x[b];

    float cwz, nwz, cuz, nuz, cwr, nwr, cur, nur;
    mmm_finish(s[0], gh, &cwz, &nwz);
    mmm_finish(s[1], gx, &cuz, &nuz);
    mmm_finish(s[2], gh, &cwr, &nwr);
    mmm_finish(s[3], gx, &cur, &nur);
    #pragma unroll
    for (int i = 0; i < 8; ++i) {
        wz[i] *= cwz; uz[i] *= cuz; wr2[i] *= cwr; ur2[i] *= cur;
    }
    float sbz = s[4], sbr2 = s[5];

    float d[2] = {0.f, 0.f};
    #pragma unroll
    for (int i = 0; i < 8; ++i) { d[0] += wz[i] * uz[i]; d[1] += wr2[i] * ur2[i]; }
    block_sums<2>(d, sbuf);
    float n1z = mob_apply(wz, uz, nwz * nwz, nuz * nuz, d[0]);
    float n1r = mob_apply(wr2, ur2, nwr * nwr, nur * nur, d[1]);

    d[0] = 0.f; d[1] = 0.f;
    #pragma unroll
    for (int i = 0; i < 8; ++i) { d[0] += wz[i] * bz[i]; d[1] += wr2[i] * br[i]; }
    block_sums<2>(d, sbuf);
    float n2z = mob_apply(wz, bz, n1z * n1z, sbz, d[0]);
    float n2r = mob_apply(wr2, br, n1r * n1r, sbr2, d[1]);

    float gz = artanh_(n2z) / n2z;
    float gr = artanh_(n2r) / n2r;
    float zz[8], v[8];
    float sv = 0.f;
    #pragma unroll
    for (int i = 0; i < 8; ++i) {
        zz[i] = sigmoid_(gz * wz[i]);
        float r = sigmoid_(gr * wr2[i]);
        v[i] = gh * hp[i] * r;
        sv += v[i] * v[i];
    }
    store_bf8(z_out + off, zz);
    block_sums<1>(&sv, sbuf);
    float nv = sqrtf(fmaxf(sv, MINN));
    float th = fminf(tanhf(nv), MAXN);
    float cr = th / nv;
    #pragma unroll
    for (int i = 0; i < 8; ++i) v[i] *= cr;
    store_bf8(rph_bf + off, v);
    store_bf8(uxr_out + off, ur2);
    if (t == 0) g_rph[b] = artanh_(th) / th;
}

// ---------- fused C: [G2 GEMM producers | fin consumers] ----------

struct FCBatch {
    const u16* rph; const u16* whT; u16* p0; u16* p1;
    const u16* uxr; const u16* z_in; const u16* h_bf;
    const float* g_rph; const float* b_h; float* out;
    FlagBlk* fl;
};

__device__ void fin_row(const FCBatch& fc, int b, float* sbuf) {
    int t = threadIdx.x;
    size_t off = (size_t)b * D + t * 8;
    int cbase = t * 8;

    float wh[8], ux[8], zz[8], hp[8], bh[8], t0[8];
    load_bf8(fc.p0 + off, wh);
    load_bf8(fc.p1 + off, t0);
    #pragma unroll
    for (int i = 0; i < 8; ++i) wh[i] += t0[i];
    load_bf8(fc.uxr + off, ux);
    load_bf8(fc.z_in + off, zz);
    load_bf8(fc.h_bf + off, hp);
    load_f8(fc.b_h + cbase, bh);

    float s[4] = {0, 0, 0, 0};
    #pragma unroll
    for (int i = 0; i < 8; ++i) {
        s[0] += wh[i] * wh[i]; s[1] += ux[i] * ux[i];
        s[2] += hp[i] * hp[i]; s[3] += bh[i] * bh[i];
    }
    block_sums<4>(s, sbuf);
    float swh = s[0], sux = s[1], shp = s[2], sbh = s[3];

    float cwh, nwh;
    mmm_finish(swh, fc.g_rph[b], &cwh, &nwh);
    #pragma unroll
    for (int i = 0; i < 8; ++i) wh[i] *= cwh;

    float d = 0.f;
    #pragma unroll
    for (int i = 0; i < 8; ++i) d += wh[i] * ux[i];
    block_sums<1>(&d, sbuf);
    float n1 = mob_apply(wh, ux, nwh * nwh, sux, d);

    d = 0.f;
    #pragma unroll
    for (int i = 0; i < 8; ++i) d += wh[i] * bh[i];
    block_sums<1>(&d, sbuf);
    float nht = mob_apply(wh, bh, n1 * n1, sbh, d);

    #pragma unroll
    for (int i = 0; i < 8; ++i) ux[i] = -hp[i];
    d = 0.f;
    #pragma unroll
    for (int i = 0; i < 8; ++i) d += ux[i] * wh[i];
    block_sums<1>(&d, sbuf);
    float nm = mob_apply(ux, wh, shp, nht * nht, d);

    float lm = artanh_(nm) / nm;
    float sv = 0.f;
    #pragma unroll
    for (int i = 0; i < 8; ++i) {
        float v = lm * ux[i] * zz[i];
        ux[i] = v;
        sv += v * v;
    }
    block_sums<1>(&sv, sbuf);
    float nv = sqrtf(fmaxf(sv, MINN));
    float th = fminf(tanhf(nv), MAXN);
    float ce = th / nv;
    #pragma unroll
    for (int i = 0; i < 8; ++i) ux[i] *= ce;

    d = 0.f;
    #pragma unroll
    for (int i = 0; i < 8; ++i) d += hp[i] * ux[i];
    block_sums<1>(&d, sbuf);
    mob_apply(hp, ux, shp, th * th, d);
    store_f8(fc.out + off, hp);
}

__global__ __launch_bounds__(256, 5) void fused_c(FCBatch fc) {
    __shared__ __align__(16) char smem[32768];
    int id = blockIdx.x;
    if (id < 512) {
        int z = id >> 8, tt = id & 255, bx = tt & 15, by = tt >> 4;
        u16* Cp = z ? fc.p1 : fc.p0;
        gemm_body<1024, u16>(fc.rph, fc.whT, Cp, z * 1024, bx, by,
                             (u16*)smem, (u16*)(smem + 16384));
        signal_cnt(&fc.fl->gcnt[by].v);
    } else {
        int f = id - 512;                    // rows 2f, 2f+1; by = f>>6
        wait_cnt(&fc.fl->gcnt[f >> 6].v, 32);
        float* sbuf = (float*)smem;
        fin_row(fc, 2 * f, sbuf);
        fin_row(fc, 2 * f + 1, sbuf);
    }
}

// ---------- launch ----------

extern "C" void kernel_launch(void* const* d_in, const int* in_sizes, int n_in,
                              void* d_out, int out_size, void* d_ws, size_t ws_size,
                              hipStream_t stream) {
    const float* hyp_x  = (const float*)d_in[0];
    const float* hidden = (const float*)d_in[1];
    const float* w_z = (const float*)d_in[2];
    const float* w_r = (const float*)d_in[3];
    const float* w_h = (const float*)d_in[4];
    const float* u_z = (const float*)d_in[5];
    const float* u_r = (const float*)d_in[6];
    const float* b_z = (const float*)d_in[7];
    const float* b_r = (const float*)d_in[8];
    const float* b_h = (const float*)d_in[9];
    float* out = (float*)d_out;

    int B = in_sizes[1] / D;   // 2048

    char* ws = (char*)d_ws;
    size_t o = 0;
    auto alloc = [&](size_t bytes) -> void* {
        void* p = ws + o;
        o += (bytes + 255) & ~(size_t)255;
        return p;
    };
    u16* wt[5];   // 0=w_zT,1=w_rT,2=w_hT,3=u_zT,4=u_rT  ([N][K] bf16)
    for (int i = 0; i < 5; ++i) wt[i] = (u16*)alloc((size_t)D * D * 2);
    u16* hx_bf = (u16*)alloc((size_t)B * D * 2);
    u16* h_bf  = (u16*)alloc((size_t)B * D * 2);
    float* g_x   = (float*)alloc((size_t)B * 4);
    float* g_h   = (float*)alloc((size_t)B * 4);
    float* g_rph = (float*)alloc((size_t)B * 4);
    u16* cz0 = (u16*)alloc((size_t)B * D * 2);   // G1 outputs, bf16
    u16* cz1 = (u16*)alloc((size_t)B * D * 2);
    u16* cz2 = (u16*)alloc((size_t)B * D * 2);
    u16* cz3 = (u16*)alloc((size_t)B * D * 2);
    u16* p0 = (u16*)alloc((size_t)B * D * 2);    // G2 K-partials, bf16
    u16* p1 = (u16*)alloc((size_t)B * D * 2);
    u16* z_buf = (u16*)alloc((size_t)B * D * 2);
    u16* uxr = (u16*)alloc((size_t)B * D * 2);
    u16* rph = (u16*)alloc((size_t)B * D * 2);
    FlagBlk* fl = (FlagBlk*)alloc(sizeof(FlagBlk));

    hipMemsetAsync(fl, 0, sizeof(FlagBlk), stream);

    // Launch 1: transposes+projection (producers) fused with G1 (consumers)
    FABatch fa;
    // transpose write order == G1 z order: w_z, u_z, w_r, u_r, then w_h (for G2)
    fa.Wsrc[0] = w_z; fa.Wdst[0] = wt[0];
    fa.Wsrc[1] = u_z; fa.Wdst[1] = wt[3];
    fa.Wsrc[2] = w_r; fa.Wdst[2] = wt[1];
    fa.Wsrc[3] = u_r; fa.Wdst[3] = wt[4];
    fa.Wsrc[4] = w_h; fa.Wdst[4] = wt[2];
    fa.hx = hyp_x; fa.h = hidden;
    fa.hx_bf = hx_bf; fa.h_bf = h_bf;
    fa.g_x = g_x; fa.g_h = g_h;
    fa.A[0] = h_bf;  fa.W[0] = wt[0]; fa.C[0] = cz0;   // h @ w_z
    fa.A[1] = hx_bf; fa.W[1] = wt[3]; fa.C[1] = cz1;   // x @ u_z
    fa.A[2] = h_bf;  fa.W[2] = wt[1]; fa.C[2] = cz2;   // h @ w_r
    fa.A[3] = hx_bf; fa.W[3] = wt[4]; fa.C[3] = cz3;   // x @ u_r
    fa.fl = fl;
    fused_a<<<dim3(2048), 256, 0, stream>>>(fa);

    // Launch 2: middle fusion
    mid_kernel<<<dim3(B), 256, 0, stream>>>(cz0, cz1, cz2, cz3, h_bf, g_x, g_h,
                                            b_z, b_r, z_buf, uxr, rph, g_rph);

    // Launch 3: G2 (2-way K-split) fused with fin (spins per 128-row group)
    FCBatch fc;
    fc.rph = rph; fc.whT = wt[2]; fc.p0 = p0; fc.p1 = p1;
    fc.uxr = uxr; fc.z_in = z_buf; fc.h_bf = h_bf;
    fc.g_rph = g_rph; fc.b_h = b_h; fc.out = out;
    fc.fl = fl;
    fused_c<<<dim3(1536), 256, 0, stream>>>(fc);
}

// Round 8
// 1340.141 us; speedup vs baseline: 1.2967x; 1.2967x over previous
//
#include <hip/hip_runtime.h>
#include <hip/hip_bf16.h>
#include <math.h>

#define EPS 1e-5f
#define MAXN (1.0f - EPS)
#define MINN 1e-10f

constexpr int D = 2048;      // Dh == Din == 2048 for this problem

typedef unsigned short u16;
typedef __bf16 bf16x8 __attribute__((ext_vector_type(8)));
typedef float floatx4 __attribute__((ext_vector_type(4)));

// ---------- small helpers ----------

__device__ __forceinline__ u16 f2bf(float f) {
    union { float f; unsigned u; } v; v.f = f;
    unsigned r = v.u + 0x7FFFu + ((v.u >> 16) & 1u);   // RNE
    return (u16)(r >> 16);
}

__device__ __forceinline__ float bf2f(u16 b) {
    union { unsigned u; float f; } v; v.u = ((unsigned)b) << 16; return v.f;
}

__device__ __forceinline__ void load_bf8(const u16* p, float* d) {
    uint4 r = *(const uint4*)p;
    unsigned w[4] = {r.x, r.y, r.z, r.w};
    #pragma unroll
    for (int i = 0; i < 4; ++i) {
        d[2 * i]     = bf2f((u16)(w[i] & 0xFFFFu));
        d[2 * i + 1] = bf2f((u16)(w[i] >> 16));
    }
}

__device__ __forceinline__ void store_bf8(u16* p, const float* s) {
    u16 pk[8];
    #pragma unroll
    for (int i = 0; i < 8; ++i) pk[i] = f2bf(s[i]);
    *(uint4*)p = *(const uint4*)pk;
}

__device__ __forceinline__ void load_f8(const float* p, float* d) {
    *(float4*)(d)     = *(const float4*)(p);
    *(float4*)(d + 4) = *(const float4*)(p + 4);
}

__device__ __forceinline__ void store_f8(float* p, const float* s) {
    *(float4*)(p)     = *(const float4*)(s);
    *(float4*)(p + 4) = *(const float4*)(s + 4);
}

__device__ __forceinline__ float artanh_(float x) {
    x = fminf(fmaxf(x, -1.0f + EPS), 1.0f - EPS);
    return 0.5f * logf((1.0f + x) / (1.0f - x));
}

__device__ __forceinline__ float sigmoid_(float x) {
    return 1.0f / (1.0f + expf(-x));
}

__device__ __forceinline__ void gl_lds16(const u16* g, u16* l) {
    __builtin_amdgcn_global_load_lds(
        (const __attribute__((address_space(1))) unsigned int*)g,
        (__attribute__((address_space(3))) unsigned int*)l, 16, 0, 0);
}

// N simultaneous block-wide sums, ONE barrier pair. 256 threads / 4 waves.
template<int N>
__device__ __forceinline__ void block_sums(float* v, float* sbuf) {
    #pragma unroll
    for (int n = 0; n < N; ++n)
        #pragma unroll
        for (int off = 32; off >= 1; off >>= 1) v[n] += __shfl_xor(v[n], off, 64);
    int w = threadIdx.x >> 6;
    __syncthreads();                       // protect sbuf from previous call
    if ((threadIdx.x & 63) == 0) {
        #pragma unroll
        for (int n = 0; n < N; ++n) sbuf[w * N + n] = v[n];
    }
    __syncthreads();
    #pragma unroll
    for (int n = 0; n < N; ++n)
        v[n] = sbuf[n] + sbuf[N + n] + sbuf[2 * N + n] + sbuf[3 * N + n];
}

__device__ __forceinline__ void mmm_finish(float sum2, float g, float* coef, float* onorm) {
    float mxn = sqrtf(fmaxf(sum2, MINN));
    float tt  = tanhf(mxn * g);
    float on  = fminf(tt, MAXN);
    *coef = on / mxn;
    *onorm = on;
}

// mob_add with analytic |num|^2 (single reduction). u <- proj(mob_add(u,v)).
__device__ __forceinline__ float mob_apply(float* u, const float* v,
                                           float u2, float v2, float duv) {
    float cu  = 1.f + 2.f * duv + v2;
    float cv  = 1.f - u2;
    float den = fmaxf(1.f + 2.f * duv + u2 * v2, MINN);
    float s2  = cu * cu * u2 + 2.f * cu * cv * duv + cv * cv * v2;
    float n   = sqrtf(fmaxf(s2 / (den * den), MINN));
    float sc  = ((n > MAXN) ? MAXN / n : 1.f) / den;
    #pragma unroll
    for (int i = 0; i < 8; ++i) u[i] = sc * (cu * u[i] + cv * v[i]);
    return fminf(n, MAXN);
}

// ---------- device-scope flag helpers (padded counters, bounded spin) ----------

struct Flag { unsigned v; unsigned pad[15]; };          // one cacheline each
struct FlagBlk { Flag pcnt; Flag wcnt[5]; Flag gcnt[16]; };

__device__ __forceinline__ void signal_cnt(unsigned* p) {
    __syncthreads();                 // all block writes done
    __threadfence();                 // device-scope release
    if (threadIdx.x == 0) atomicAdd(p, 1u);
}

__device__ __forceinline__ void wait_cnt(unsigned* p, unsigned tgt) {
    if (threadIdx.x == 0) {
        unsigned n = 0;
        while (__hip_atomic_load(p, __ATOMIC_RELAXED, __HIP_MEMORY_SCOPE_AGENT) < tgt
               && n < (1u << 22)) {   // bounded: cannot hang
            __builtin_amdgcn_s_sleep(8);
            ++n;
        }
    }
    __syncthreads();
    __threadfence();                 // device-scope acquire
}

// ---------- transpose helper: one 64x64 f32 -> bf16^T tile through LDS ----------

__device__ __forceinline__ void trans_tile(const float* W, u16* Wt,
                                           int n0, int k0, float* tile) {
    int t = threadIdx.x;
    int lr = t >> 4, lc = (t & 15) * 4;
    #pragma unroll
    for (int p = 0; p < 4; ++p) {
        int r = lr + p * 16;
        float4 v = *(const float4*)(W + (size_t)(k0 + r) * D + n0 + lc);
        tile[r * 65 + lc + 0] = v.x;
        tile[r * 65 + lc + 1] = v.y;
        tile[r * 65 + lc + 2] = v.z;
        tile[r * 65 + lc + 3] = v.w;
    }
    __syncthreads();
    int wn = t >> 3, ws = (t & 7) * 8;
    #pragma unroll
    for (int p = 0; p < 2; ++p) {
        int n = wn + p * 32;
        u16 pk[8];
        #pragma unroll
        for (int j = 0; j < 8; ++j) pk[j] = f2bf(tile[(ws + j) * 65 + n]);
        *(uint4*)(Wt + (size_t)(n0 + n) * D + k0 + ws) = *(uint4*)pk;
    }
}

// ---------- GEMM core (m97-style, BK=64, swizzled global_load_lds) ----------

template<int KLEN, typename CT>
__device__ __forceinline__ void gemm_body(const u16* __restrict__ A,
                                          const u16* __restrict__ W,
                                          CT* __restrict__ C, int koff,
                                          int bxi, int byi,
                                          u16* As, u16* Ws) {
    int t = threadIdx.x;
    int wave = t >> 6, lane = t & 63;
    int wr = wave >> 1, wc = wave & 1;       // 2x2 wave grid, each 64x64
    int quad = lane >> 4, l16 = lane & 15;
    int brow = byi * 128, bcol = bxi * 128;

    int srow = 32 * wave + (lane >> 3);
    int sseg = (lane & 7) ^ ((lane >> 3) & 7);
    const u16* pa = A + (size_t)(brow + srow) * D + koff + sseg * 8;
    const u16* pw = W + (size_t)(bcol + srow) * D + koff + sseg * 8;
    u16* lbA = &As[wave * 2048];             // wave-uniform LDS bases
    u16* lbW = &Ws[wave * 2048];

    floatx4 acc[4][4];
    #pragma unroll
    for (int i = 0; i < 4; ++i)
        #pragma unroll
        for (int j = 0; j < 4; ++j)
            #pragma unroll
            for (int e = 0; e < 4; ++e) acc[i][j][e] = 0.f;

    int xsw = l16 & 7;                       // fragment-read swizzle term

    for (int k0 = 0; k0 < KLEN; k0 += 64) {
        __syncthreads();
        #pragma unroll
        for (int i = 0; i < 4; ++i) {
            gl_lds16(pa + (size_t)(8 * i) * D + k0, lbA + i * 512);
            gl_lds16(pw + (size_t)(8 * i) * D + k0, lbW + i * 512);
        }
        __syncthreads();

        #pragma unroll
        for (int kk = 0; kk < 2; ++kk) {
            bf16x8 af[4], bfv[4];
            int ps = ((kk * 4 + quad) ^ xsw) * 8;
            #pragma unroll
            for (int i = 0; i < 4; ++i)
                af[i] = *(const bf16x8*)(&As[(wr * 64 + i * 16 + l16) * 64 + ps]);
            #pragma unroll
            for (int j = 0; j < 4; ++j)
                bfv[j] = *(const bf16x8*)(&Ws[(wc * 64 + j * 16 + l16) * 64 + ps]);
            #pragma unroll
            for (int i = 0; i < 4; ++i)
                #pragma unroll
                for (int j = 0; j < 4; ++j)
                    acc[i][j] = __builtin_amdgcn_mfma_f32_16x16x32_bf16(af[i], bfv[j], acc[i][j], 0, 0, 0);
        }
    }

    #pragma unroll
    for (int i = 0; i < 4; ++i) {
        #pragma unroll
        for (int j = 0; j < 4; ++j) {
            int row = brow + wr * 64 + i * 16 + quad * 4;
            int col = bcol + wc * 64 + j * 16 + l16;
            #pragma unroll
            for (int r = 0; r < 4; ++r) {
                float val = acc[i][j][r];
                if constexpr (sizeof(CT) == 2)
                    C[(size_t)(row + r) * D + col] = (CT)f2bf(val);
                else
                    C[(size_t)(row + r) * D + col] = (CT)val;
            }
        }
    }
}

// ---------- fused A: [1024 transpose+proj producers | 256 G1 GEMM consumers] ----
// Producers (ids 0..1023): 2 proj rows, then 5 weight tiles in G1 z order.
// Consumers (ids 1024..1279): each runs 4 GEMM tiles of one z after its weight
// and the projections complete. 256 spinners << 1024 worst-case resident blocks
// (4 blocks/CU at 32KB LDS) => a producer can always run: deadlock-free.
// NO min-waves launch bound: gemm_body needs its ~84 VGPRs (R7 lesson: a
// forced cap spilled acc to scratch, 679MB writes, 5.5x regression).

struct FABatch {
    const float* Wsrc[5]; u16* Wdst[5];       // order: w_z,u_z,w_r,u_r,w_h
    const float* hx; const float* h;
    u16* hx_bf; u16* h_bf; float* g_x; float* g_h;
    const u16* A[4]; const u16* W[4]; u16* C[4];
    FlagBlk* fl;
};

__global__ __launch_bounds__(256) void fused_a(FABatch fa) {
    __shared__ __align__(16) char smem[32768];
    int id = blockIdx.x;
    if (id < 1024) {
        float* tile = (float*)smem;
        // projection: rows 2*id, 2*id+1 (hx and h batched)
        #pragma unroll
        for (int rr = 0; rr < 2; ++rr) {
            int b = id * 2 + rr;
            size_t off = (size_t)b * D + threadIdx.x * 8;
            float xv[8], hv[8];
            load_f8(fa.hx + off, xv);
            load_f8(fa.h + off, hv);
            float s[2] = {0.f, 0.f};
            #pragma unroll
            for (int i = 0; i < 8; ++i) { s[0] += xv[i] * xv[i]; s[1] += hv[i] * hv[i]; }
            block_sums<2>(s, tile);
            float nx = sqrtf(fmaxf(s[0], MINN));
            float scx = (nx > MAXN) ? MAXN / nx : 1.0f;
            float nh = sqrtf(fmaxf(s[1], MINN));
            float sch = (nh > MAXN) ? MAXN / nh : 1.0f;
            #pragma unroll
            for (int i = 0; i < 8; ++i) { xv[i] *= scx; hv[i] *= sch; }
            store_bf8(fa.hx_bf + off, xv);
            store_bf8(fa.h_bf + off, hv);
            if (threadIdx.x == 0) {
                float xn = fminf(nx, MAXN), hn = fminf(nh, MAXN);
                fa.g_x[b] = artanh_(xn) / xn;
                fa.g_h[b] = artanh_(hn) / hn;
            }
        }
        signal_cnt(&fa.fl->pcnt.v);

        int n0 = (id & 31) * 64, k0 = (id >> 5) * 64;
        for (int s = 0; s < 5; ++s) {
            trans_tile(fa.Wsrc[s], fa.Wdst[s], n0, k0, tile);
            signal_cnt(&fa.fl->wcnt[s].v);   // syncthreads inside protects tile reuse
        }
    } else {
        int c = id - 1024;                   // 0..255
        int z = c & 3;                       // 64 consumers per z, 4 tiles each
        wait_cnt(&fa.fl->wcnt[z].v, 1024);
        wait_cnt(&fa.fl->pcnt.v, 1024);
        #pragma unroll
        for (int i = 0; i < 4; ++i) {
            int tt = (c >> 2) * 4 + i;       // 0..255
            int bx = tt & 15, by = tt >> 4;
            gemm_body<2048, u16>(fa.A[z], fa.W[z], fa.C[z], 0, bx, by,
                                 (u16*)smem, (u16*)(smem + 16384));
        }
    }
}

// ---------- K4: fused middle (finish 4 matvecs, z, r, r_point_h) ----------

__global__ __launch_bounds__(256) void mid_kernel(
    const u16* __restrict__ c_wz, const u16* __restrict__ c_uz,
    const u16* __restrict__ c_wr, const u16* __restrict__ c_ur,
    const u16* __restrict__ h_bf,
    const float* __restrict__ g_x, const float* __restrict__ g_h,
    const float* __restrict__ b_z, const float* __restrict__ b_r,
    u16* __restrict__ z_out, u16* __restrict__ uxr_out,
    u16* __restrict__ rph_bf, float* __restrict__ g_rph) {
    __shared__ float sbuf[24];
    int b = blockIdx.x, t = threadIdx.x;
    size_t off = (size_t)b * D + t * 8;
    int cbase = t * 8;

    float wz[8], uz[8], wr2[8], ur2[8], hp[8], bz[8], br[8];
    load_bf8(c_wz + off, wz);
    load_bf8(c_uz + off, uz);
    load_bf8(c_wr + off, wr2);
    load_bf8(c_ur + off, ur2);
    load_bf8(h_bf + off, hp);
    load_f8(b_z + cbase, bz);
    load_f8(b_r + cbase, br);

    float s[6] = {0, 0, 0, 0, 0, 0};
    #pragma unroll
    for (int i = 0; i < 8; ++i) {
        s[0] += wz[i] * wz[i];  s[1] += uz[i] * uz[i];
        s[2] += wr2[i] * wr2[i]; s[3] += ur2[i] * ur2[i];
        s[4] += bz[i] * bz[i];  s[5] += br[i] * br[i];
    }
    block_sums<6>(s, sbuf);
    float gh = g_h[b], gx = g_x[b];

    float cwz, nwz, cuz, nuz, cwr, nwr, cur, nur;
    mmm_finish(s[0], gh, &cwz, &nwz);
    mmm_finish(s[1], gx, &cuz, &nuz);
    mmm_finish(s[2], gh, &cwr, &nwr);
    mmm_finish(s[3], gx, &cur, &nur);
    #pragma unroll
    for (int i = 0; i < 8; ++i) {
        wz[i] *= cwz; uz[i] *= cuz; wr2[i] *= cwr; ur2[i] *= cur;
    }
    float sbz = s[4], sbr2 = s[5];

    float d[2] = {0.f, 0.f};
    #pragma unroll
    for (int i = 0; i < 8; ++i) { d[0] += wz[i] * uz[i]; d[1] += wr2[i] * ur2[i]; }
    block_sums<2>(d, sbuf);
    float n1z = mob_apply(wz, uz, nwz * nwz, nuz * nuz, d[0]);
    float n1r = mob_apply(wr2, ur2, nwr * nwr, nur * nur, d[1]);

    d[0] = 0.f; d[1] = 0.f;
    #pragma unroll
    for (int i = 0; i < 8; ++i) { d[0] += wz[i] * bz[i]; d[1] += wr2[i] * br[i]; }
    block_sums<2>(d, sbuf);
    float n2z = mob_apply(wz, bz, n1z * n1z, sbz, d[0]);
    float n2r = mob_apply(wr2, br, n1r * n1r, sbr2, d[1]);

    float gz = artanh_(n2z) / n2z;
    float gr = artanh_(n2r) / n2r;
    float zz[8], v[8];
    float sv = 0.f;
    #pragma unroll
    for (int i = 0; i < 8; ++i) {
        zz[i] = sigmoid_(gz * wz[i]);
        float r = sigmoid_(gr * wr2[i]);
        v[i] = gh * hp[i] * r;
        sv += v[i] * v[i];
    }
    store_bf8(z_out + off, zz);
    block_sums<1>(&sv, sbuf);
    float nv = sqrtf(fmaxf(sv, MINN));
    float th = fminf(tanhf(nv), MAXN);
    float cr = th / nv;
    #pragma unroll
    for (int i = 0; i < 8; ++i) v[i] *= cr;
    store_bf8(rph_bf + off, v);
    store_bf8(uxr_out + off, ur2);
    if (t == 0) g_rph[b] = artanh_(th) / th;
}

// ---------- fused C: [512 G2 GEMM producers | 512 fin consumers] ----------
// 512 spinners << 1024 worst-case resident: deadlock-free.

struct FCBatch {
    const u16* rph; const u16* whT; u16* p0; u16* p1;
    const u16* uxr; const u16* z_in; const u16* h_bf;
    const float* g_rph; const float* b_h; float* out;
    FlagBlk* fl;
};

__device__ void fin_row(const FCBatch& fc, int b, float* sbuf) {
    int t = threadIdx.x;
    size_t off = (size_t)b * D + t * 8;
    int cbase = t * 8;

    float wh[8], ux[8], zz[8], hp[8], bh[8], t0[8];
    load_bf8(fc.p0 + off, wh);
    load_bf8(fc.p1 + off, t0);
    #pragma unroll
    for (int i = 0; i < 8; ++i) wh[i] += t0[i];
    load_bf8(fc.uxr + off, ux);
    load_bf8(fc.z_in + off, zz);
    load_bf8(fc.h_bf + off, hp);
    load_f8(fc.b_h + cbase, bh);

    float s[4] = {0, 0, 0, 0};
    #pragma unroll
    for (int i = 0; i < 8; ++i) {
        s[0] += wh[i] * wh[i]; s[1] += ux[i] * ux[i];
        s[2] += hp[i] * hp[i]; s[3] += bh[i] * bh[i];
    }
    block_sums<4>(s, sbuf);
    float swh = s[0], sux = s[1], shp = s[2], sbh = s[3];

    float cwh, nwh;
    mmm_finish(swh, fc.g_rph[b], &cwh, &nwh);
    #pragma unroll
    for (int i = 0; i < 8; ++i) wh[i] *= cwh;

    float d = 0.f;
    #pragma unroll
    for (int i = 0; i < 8; ++i) d += wh[i] * ux[i];
    block_sums<1>(&d, sbuf);
    float n1 = mob_apply(wh, ux, nwh * nwh, sux, d);

    d = 0.f;
    #pragma unroll
    for (int i = 0; i < 8; ++i) d += wh[i] * bh[i];
    block_sums<1>(&d, sbuf);
    float nht = mob_apply(wh, bh, n1 * n1, sbh, d);

    #pragma unroll
    for (int i = 0; i < 8; ++i) ux[i] = -hp[i];
    d = 0.f;
    #pragma unroll
    for (int i = 0; i < 8; ++i) d += ux[i] * wh[i];
    block_sums<1>(&d, sbuf);
    float nm = mob_apply(ux, wh, shp, nht * nht, d);

    float lm = artanh_(nm) / nm;
    float sv = 0.f;
    #pragma unroll
    for (int i = 0; i < 8; ++i) {
        float v = lm * ux[i] * zz[i];
        ux[i] = v;
        sv += v * v;
    }
    block_sums<1>(&sv, sbuf);
    float nv = sqrtf(fmaxf(sv, MINN));
    float th = fminf(tanhf(nv), MAXN);
    float ce = th / nv;
    #pragma unroll
    for (int i = 0; i < 8; ++i) ux[i] *= ce;

    d = 0.f;
    #pragma unroll
    for (int i = 0; i < 8; ++i) d += hp[i] * ux[i];
    block_sums<1>(&d, sbuf);
    mob_apply(hp, ux, shp, th * th, d);
    store_f8(fc.out + off, hp);
}

__global__ __launch_bounds__(256) void fused_c(FCBatch fc) {
    __shared__ __align__(16) char smem[32768];
    int id = blockIdx.x;
    if (id < 512) {
        int z = id >> 8, tt = id & 255, bx = tt & 15, by = tt >> 4;
        u16* Cp = z ? fc.p1 : fc.p0;
        gemm_body<1024, u16>(fc.rph, fc.whT, Cp, z * 1024, bx, by,
                             (u16*)smem, (u16*)(smem + 16384));
        signal_cnt(&fc.fl->gcnt[by].v);
    } else {
        int f = id - 512;                    // rows 4f..4f+3 (same 128-row group)
        wait_cnt(&fc.fl->gcnt[f >> 5].v, 32);
        float* sbuf = (float*)smem;
        #pragma unroll
        for (int r = 0; r < 4; ++r) fin_row(fc, 4 * f + r, sbuf);
    }
}

// ---------- launch ----------

extern "C" void kernel_launch(void* const* d_in, const int* in_sizes, int n_in,
                              void* d_out, int out_size, void* d_ws, size_t ws_size,
                              hipStream_t stream) {
    const float* hyp_x  = (const float*)d_in[0];
    const float* hidden = (const float*)d_in[1];
    const float* w_z = (const float*)d_in[2];
    const float* w_r = (const float*)d_in[3];
    const float* w_h = (const float*)d_in[4];
    const float* u_z = (const float*)d_in[5];
    const float* u_r = (const float*)d_in[6];
    const float* b_z = (const float*)d_in[7];
    const float* b_r = (const float*)d_in[8];
    const float* b_h = (const float*)d_in[9];
    float* out = (float*)d_out;

    int B = in_sizes[1] / D;   // 2048

    char* ws = (char*)d_ws;
    size_t o = 0;
    auto alloc = [&](size_t bytes) -> void* {
        void* p = ws + o;
        o += (bytes + 255) & ~(size_t)255;
        return p;
    };
    u16* wt[5];   // 0=w_zT,1=w_rT,2=w_hT,3=u_zT,4=u_rT  ([N][K] bf16)
    for (int i = 0; i < 5; ++i) wt[i] = (u16*)alloc((size_t)D * D * 2);
    u16* hx_bf = (u16*)alloc((size_t)B * D * 2);
    u16* h_bf  = (u16*)alloc((size_t)B * D * 2);
    float* g_x   = (float*)alloc((size_t)B * 4);
    float* g_h   = (float*)alloc((size_t)B * 4);
    float* g_rph = (float*)alloc((size_t)B * 4);
    u16* cz0 = (u16*)alloc((size_t)B * D * 2);   // G1 outputs, bf16
    u16* cz1 = (u16*)alloc((size_t)B * D * 2);
    u16* cz2 = (u16*)alloc((size_t)B * D * 2);
    u16* cz3 = (u16*)alloc((size_t)B * D * 2);
    u16* p0 = (u16*)alloc((size_t)B * D * 2);    // G2 K-partials, bf16
    u16* p1 = (u16*)alloc((size_t)B * D * 2);
    u16* z_buf = (u16*)alloc((size_t)B * D * 2);
    u16* uxr = (u16*)alloc((size_t)B * D * 2);
    u16* rph = (u16*)alloc((size_t)B * D * 2);
    FlagBlk* fl = (FlagBlk*)alloc(sizeof(FlagBlk));

    hipMemsetAsync(fl, 0, sizeof(FlagBlk), stream);

    // Launch 1: transposes+projection (producers) fused with G1 (consumers)
    FABatch fa;
    fa.Wsrc[0] = w_z; fa.Wdst[0] = wt[0];
    fa.Wsrc[1] = u_z; fa.Wdst[1] = wt[3];
    fa.Wsrc[2] = w_r; fa.Wdst[2] = wt[1];
    fa.Wsrc[3] = u_r; fa.Wdst[3] = wt[4];
    fa.Wsrc[4] = w_h; fa.Wdst[4] = wt[2];
    fa.hx = hyp_x; fa.h = hidden;
    fa.hx_bf = hx_bf; fa.h_bf = h_bf;
    fa.g_x = g_x; fa.g_h = g_h;
    fa.A[0] = h_bf;  fa.W[0] = wt[0]; fa.C[0] = cz0;   // h @ w_z
    fa.A[1] = hx_bf; fa.W[1] = wt[3]; fa.C[1] = cz1;   // x @ u_z
    fa.A[2] = h_bf;  fa.W[2] = wt[1]; fa.C[2] = cz2;   // h @ w_r
    fa.A[3] = hx_bf; fa.W[3] = wt[4]; fa.C[3] = cz3;   // x @ u_r
    fa.fl = fl;
    fused_a<<<dim3(1280), 256, 0, stream>>>(fa);

    // Launch 2: middle fusion
    mid_kernel<<<dim3(B), 256, 0, stream>>>(cz0, cz1, cz2, cz3, h_bf, g_x, g_h,
                                            b_z, b_r, z_buf, uxr, rph, g_rph);

    // Launch 3: G2 (2-way K-split) fused with fin (spins per 128-row group)
    FCBatch fc;
    fc.rph = rph; fc.whT = wt[2]; fc.p0 = p0; fc.p1 = p1;
    fc.uxr = uxr; fc.z_in = z_buf; fc.h_bf = h_bf;
    fc.g_rph = g_rph; fc.b_h = b_h; fc.out = out;
    fc.fl = fl;
    fused_c<<<dim3(1024), 256, 0, stream>>>(fc);
}